// Round 4
// baseline (174.538 us; speedup 1.0000x reference)
//
#include <hip/hip_runtime.h>
#include <stdint.h>

#define EPSN 1e-12f

typedef float f32x16 __attribute__((ext_vector_type(16)));
typedef float f32x4 __attribute__((ext_vector_type(4)));
typedef __bf16 bf16x8 __attribute__((ext_vector_type(8)));

// ---- bf16 helpers (round-to-nearest-even) ----
__device__ __forceinline__ unsigned short f2bf(float f) {
  union { float f; unsigned int u; } v; v.f = f;
  unsigned int u = v.u + 0x7FFFu + ((v.u >> 16) & 1u);
  return (unsigned short)(u >> 16);
}

// ---- workspace layout (ushort offsets) ----
// Fragment-major packed weights for 32x32x16 MFMA, K padded 258(+bias)->272:
//   addr = ((tile*NKS + ks)*64 + hi*32 + col)*8 + j
//   value = W[o = tile*32 + col][k = ks*16 + hi*8 + j]  (k=258 bias, >258 zero)
#define NKS 17
#define WQF_OFF 0
#define WKF_OFF (32 * NKS * 64 * 8)
#define WVP_OFF (2 * 32 * NKS * 64 * 8)

// Generation-based grid barrier counter: zero at module load, monotonic
// across graph replays (each launch consumes one generation of 512).
__device__ uint32_t g_bar = 0;

#define NBLK 512

// =====================================================================
// mono kernel: 512 blocks x 1024 threads, plain launch (graph-capture
// safe), 2 blocks/CU resident (32 VGPR + 32 AGPR, ~27KB LDS) => all 512
// blocks co-resident by static limits, so a software grid barrier is
// deadlock-free.
// Phase 0: this block's 1/512 share of weight packing (wq/wk ->
//   fragment-major bf16) + WVt (wout@v^T), PLUS staging of this block's
//   xp tile from x (overlaps the HBM x-read with other blocks' prep).
// software grid barrier (device-scope atomics + fences, ROCm CG recipe)
// Phase 1: R2 fused body (q K-loop, q-norm, k K-loop, attn, epilogue).
// =====================================================================
#define PXB 32   // pixels per block
#define KP 296   // xp row stride in shorts
#define QS 34    // qbar row stride (floats)
#define AT 76    // attnM row stride (shorts)

__global__ __launch_bounds__(1024, 8) void mono_kernel(
    const float* __restrict__ x, const float* __restrict__ pos,
    const float* __restrict__ wq, const float* __restrict__ bq,
    const float* __restrict__ wk, const float* __restrict__ bk,
    const float* __restrict__ v, const float* __restrict__ wout,
    const float* __restrict__ bout,
    unsigned short* __restrict__ wsp, float* __restrict__ out) {
  __shared__ __align__(16) unsigned short xp[PXB * KP];        // 18944 B
  __shared__ __align__(16) float qbarL[16 * QS];               // 2176 B
  __shared__ __align__(16) unsigned short attnM[PXB * AT];     // 4864 B
  __shared__ float boutL[256];                                 // 1024 B

  const int tid = threadIdx.x;
  const int lane = tid & 63;
  const int wid = __builtin_amdgcn_readfirstlane(tid >> 6);
  const int px = lane & 31, q2 = lane >> 5;
  const int bid = blockIdx.x;
  const int P0 = bid * PXB;
  const int b = P0 >> 12, s0 = P0 & 4095;

  // ---------------- phase 0a: weight packing share ----------------
  // block bid packs 4 o-rows of (bid<256 ? wq : wk).
  {
    int isK = bid >= 256;
    int ob = (bid & 255) * 4;
    const float* w = isK ? wk : wq;
    const float* bb = isK ? bk : bq;
    unsigned short* dst = wsp + (isK ? WKF_OFF : WQF_OFF);
    // k 0..257 as 129 float2 per row (516 items)
    if (tid < 4 * 129) {
      int i = tid;
      int r = i / 129, q = i - r * 129;
      int o = ob + r, k = q * 2;
      float2 w2 = *(const float2*)(w + o * 258 + k);
      int g = o >> 5, col = o & 31;
      int ks = k >> 4, hi = (k >> 3) & 1, j = k & 7;
      uint32_t pk = (uint32_t)f2bf(w2.x) | ((uint32_t)f2bf(w2.y) << 16);
      *(uint32_t*)(dst + (((g * NKS + ks) * 64 + hi * 32 + col) << 3) + j) = pk;
    }
    // k 258 (bias) and 259..271 (zero): 56 items, threads 516..571
    if (tid >= 516 && tid < 516 + 4 * 14) {
      int i = tid - 516;
      int r = i / 14, kk = 258 + (i - r * 14);
      int o = ob + r;
      int g = o >> 5, col = o & 31;
      int ks = kk >> 4, hi = (kk >> 3) & 1, j = kk & 7;
      dst[(((g * NKS + ks) * 64 + hi * 32 + col) << 3) + j] =
          (kk == 258) ? f2bf(bb[o]) : (unsigned short)0;
    }
  }
  // ---------------- phase 0b: WVt share (wout @ v^T, bf16) ----------------
  if (tid < 512) {
    int idx = bid * 512 + tid;  // [0, 262144)
    int fc = idx & 15, m = (idx >> 4) & 63, o = idx >> 10;
    const f32x4* wo = (const f32x4*)(wout + o * 256 + fc * 16);
    const f32x4* vm = (const f32x4*)(v + m * 256 + fc * 16);
    float s = 0.f;
#pragma unroll
    for (int f = 0; f < 4; ++f) {
      f32x4 a = wo[f], bvv = vm[f];
      s += a[0]*bvv[0] + a[1]*bvv[1] + a[2]*bvv[2] + a[3]*bvv[3];
    }
    s += __shfl_xor(s, 1, 64);
    s += __shfl_xor(s, 2, 64);
    s += __shfl_xor(s, 4, 64);
    s += __shfl_xor(s, 8, 64);
    if (fc == 0) wsp[WVP_OFF + o * 64 + m] = f2bf(s);
  }

  // ---------------- phase 0c: stage xp[p][c] (overlaps prep) ----------------
  uint32_t* xp32 = (uint32_t*)xp;
  {
    const float* xrow = x + b * 256 * 4096 + s0;
    float v0[4], v1[4];
#pragma unroll
    for (int it = 0; it < 4; ++it) {
      int item = tid + it * 1024;                 // 0..4095
      int pp = item & 31, dcol = item >> 5;       // dcol 0..127
      v0[it] = xrow[(2 * dcol) * 4096 + pp];
      v1[it] = xrow[(2 * dcol + 1) * 4096 + pp];
    }
#pragma unroll
    for (int it = 0; it < 4; ++it) {
      int item = tid + it * 1024;
      int pp = item & 31, dcol = item >> 5;
      xp32[pp * 148 + dcol] =
          (uint32_t)f2bf(v0[it]) | ((uint32_t)f2bf(v1[it]) << 16);
    }
    // tail cols: dcol 128 = (pos_y,pos_x), 129 = (1,0) bias, 130..135 = 0
    if (tid < 256) {
      int pp = tid & 31, dcol = 128 + (tid >> 5);
      float t0 = 0.f, t1 = 0.f;
      if (dcol == 128) { t0 = pos[s0 + pp]; t1 = pos[4096 + s0 + pp]; }
      else if (dcol == 129) { t0 = 1.0f; }
      xp32[pp * 148 + dcol] = (uint32_t)f2bf(t0) | ((uint32_t)f2bf(t1) << 16);
    }
  }
  if (tid < 256) boutL[tid] = bout[tid];
  for (int i = tid; i < 16 * QS; i += 1024) qbarL[i] = 0.f;

  // ---------------- software grid barrier ----------------
  // All 512 blocks are co-resident (2/CU by static limits), so this
  // cannot deadlock. Generation-based: no reset needed across replays.
  __syncthreads();                       // all block stores drained
  if (tid == 0) {
    __threadfence();                     // release: make wsp writes visible
    uint32_t old = atomicAdd(&g_bar, 1u);
    uint32_t target = ((old >> 9) + 1u) << 9;   // this launch's generation
    while (atomicAdd(&g_bar, 0u) < target) __builtin_amdgcn_s_sleep(2);
    __threadfence();                     // acquire: invalidate stale caches
  }
  __syncthreads();

  // Per-wave A-stream bases (tile0 = 2*wid, tile1 = 2*wid+1; +lane frag)
  const int wtoff = (2 * wid) * NKS * 512 + lane * 8;
  const unsigned short* wqf = wsp + WQF_OFF + wtoff;
  const unsigned short* wkf = wsp + WKF_OFF + wtoff;

// K-loop: 2 MFMAs per ks per wave; loads straight global(L2)->VGPR,
// compiler-scheduled within the 8-wave register budget.
#define PHASE(WB) do {                                                    \
    _Pragma("unroll")                                                     \
    for (int ks = 0; ks < NKS; ++ks) {                                    \
      bf16x8 _A0 = *(const bf16x8*)((WB) + ks * 512);                     \
      bf16x8 _A1 = *(const bf16x8*)((WB) + NKS * 512 + ks * 512);         \
      bf16x8 _b0 = *(const bf16x8*)&xp[px * KP + ks * 16 + q2 * 8];       \
      acc0 = __builtin_amdgcn_mfma_f32_32x32x16_bf16(_A0, _b0, acc0, 0, 0, 0); \
      acc1 = __builtin_amdgcn_mfma_f32_32x32x16_bf16(_A1, _b0, acc1, 0, 0, 0); \
    }                                                                     \
  } while (0)

  // ================= q phase =================
  f32x16 acc0 = (f32x16)0.f, acc1 = (f32x16)0.f;
  PHASE(wqf);

  // normalize per m; accumulate qbar partials
  {
    float qsum[8];
#pragma unroll
    for (int r = 0; r < 8; ++r) qsum[r] = 0.f;
#pragma unroll
    for (int ot = 0; ot < 2; ++ot) {
      const f32x16 a = ot ? acc1 : acc0;
      float s20 = 0.f, s21 = 0.f;
#pragma unroll
      for (int r = 0; r < 8; ++r) {
        s20 = fmaf(a[r], a[r], s20);
        s21 = fmaf(a[r + 8], a[r + 8], s21);
      }
      s20 += __shfl_xor(s20, 32, 64);
      s21 += __shfl_xor(s21, 32, 64);
      float i0 = 1.0f / fmaxf(sqrtf(s20), EPSN);
      float i1 = 1.0f / fmaxf(sqrtf(s21), EPSN);
#pragma unroll
      for (int r = 0; r < 8; ++r) qsum[r] += a[r] * i0 + a[r + 8] * i1;
    }
#pragma unroll
    for (int r = 0; r < 8; ++r) {
      int j = (r & 3) + ((r >> 2) << 3) + (q2 << 2);
      atomicAdd(&qbarL[j * QS + px], qsum[r] * (1.0f / 64.0f));
    }
  }
  // NO barrier here: k-phase MFMAs don't read qbarL; the barrier below
  // (after the k K-loop) orders the qbar atomics vs the qb reads.

  // ================= k phase =================
  acc0 = (f32x16)0.f; acc1 = (f32x16)0.f;
  PHASE(wkf);
  __syncthreads();

  {
    float qb[8];
#pragma unroll
    for (int r = 0; r < 8; ++r) {
      int j = (r & 3) + ((r >> 2) << 3) + (q2 << 2);
      qb[r] = qbarL[j * QS + px];
    }
#pragma unroll
    for (int ot = 0; ot < 2; ++ot) {
      const f32x16 a = ot ? acc1 : acc0;
      float s20 = 0.f, s21 = 0.f, sp0 = 0.f, sp1 = 0.f;
#pragma unroll
      for (int r = 0; r < 8; ++r) {
        s20 = fmaf(a[r], a[r], s20);         sp0 = fmaf(qb[r], a[r], sp0);
        s21 = fmaf(a[r + 8], a[r + 8], s21); sp1 = fmaf(qb[r], a[r + 8], sp1);
      }
      s20 += __shfl_xor(s20, 32, 64);
      s21 += __shfl_xor(s21, 32, 64);
      sp0 += __shfl_xor(sp0, 32, 64);
      sp1 += __shfl_xor(sp1, 32, 64);
      if (q2 == 0) {
        int m0 = wid * 4 + ot * 2;
        attnM[px * AT + m0]     = f2bf(sp0 / fmaxf(sqrtf(s20), EPSN));
        attnM[px * AT + m0 + 1] = f2bf(sp1 / fmaxf(sqrtf(s21), EPSN));
      }
    }
  }
  __syncthreads();

  // ================= epilogue: out = x + bout + WVt @ attn =================
  if (wid < 8) {
    const int otile = wid;
    f32x16 e = (f32x16)0.f;
    const unsigned short* wv = wsp + WVP_OFF + (otile * 32 + px) * 64 + q2 * 8;
    const unsigned short* ab = &attnM[px * AT + q2 * 8];
#pragma unroll
    for (int ks = 0; ks < 4; ++ks) {
      bf16x8 av = *(const bf16x8*)(wv + ks * 16);
      bf16x8 bv = *(const bf16x8*)(ab + ks * 16);
      e = __builtin_amdgcn_mfma_f32_32x32x16_bf16(av, bv, e, 0, 0, 0);
    }
#pragma unroll
    for (int r = 0; r < 16; ++r) {
      const int o = otile * 32 + (r & 3) + ((r >> 2) << 3) + (q2 << 2);
      const int gi = (b * 256 + o) * 4096 + s0 + px;
      out[gi] = x[gi] + boutL[o] + e[r];
    }
  }
#undef PHASE
}

// =====================================================================
extern "C" void kernel_launch(void* const* d_in, const int* in_sizes, int n_in,
                              void* d_out, int out_size, void* d_ws, size_t ws_size,
                              hipStream_t stream) {
  const float* x    = (const float*)d_in[0];
  const float* pos  = (const float*)d_in[1];
  const float* wq   = (const float*)d_in[2];
  const float* bq   = (const float*)d_in[3];
  const float* wk   = (const float*)d_in[4];
  const float* bk   = (const float*)d_in[5];
  const float* v    = (const float*)d_in[6];
  const float* wout = (const float*)d_in[7];
  const float* bout = (const float*)d_in[8];
  float* out = (float*)d_out;
  unsigned short* wsp = (unsigned short*)d_ws;

  hipLaunchKernelGGL(mono_kernel, dim3(NBLK), dim3(1024), 0, stream,
                     x, pos, wq, bq, wk, bk, v, wout, bout, wsp, out);
}

// Round 5
// 129.000 us; speedup vs baseline: 1.3530x; 1.3530x over previous
//
#include <hip/hip_runtime.h>
#include <stdint.h>

#define EPSN 1e-12f

typedef float f32x16 __attribute__((ext_vector_type(16)));
typedef float f32x4 __attribute__((ext_vector_type(4)));
typedef __bf16 bf16x8 __attribute__((ext_vector_type(8)));

// ---- bf16 helpers (round-to-nearest-even) ----
__device__ __forceinline__ unsigned short f2bf(float f) {
  union { float f; unsigned int u; } v; v.f = f;
  unsigned int u = v.u + 0x7FFFu + ((v.u >> 16) & 1u);
  return (unsigned short)(u >> 16);
}

// ---- workspace layout (ushort offsets) ----
// Fragment-major packed weights for 32x32x16 MFMA, K padded 258(+bias)->272:
//   addr = ((tile*NKS + ks)*64 + hi*32 + col)*8 + j
//   value = W[o = tile*32 + col][k = ks*16 + hi*8 + j]  (k=258 bias, >258 zero)
#define NKS 17
#define WQF_OFF 0
#define WKF_OFF (32 * NKS * 64 * 8)
#define WVP_OFF (2 * 32 * NKS * 64 * 8)

// =====================================================================
// prep: blocks [0,512) pack wq/wk (4 o-rows each); [512,1536) WVt.
// (unchanged from R2 — verified passing)
// =====================================================================
__global__ __launch_bounds__(256) void prep_kernel(
    const float* __restrict__ wq, const float* __restrict__ bq,
    const float* __restrict__ wk, const float* __restrict__ bk,
    const float* __restrict__ v, const float* __restrict__ wout,
    unsigned short* __restrict__ wsp) {
  int bid = blockIdx.x;
  if (bid < 512) {
    int isK = bid >= 256;
    int ob = (bid & 255) * 4;
    const float* w = isK ? wk : wq;
    const float* bb = isK ? bk : bq;
    unsigned short* dst = wsp + (isK ? WKF_OFF : WQF_OFF);
    // k 0..257 as 129 float2 per row
    for (int i = threadIdx.x; i < 4 * 129; i += 256) {
      int r = i / 129, q = i - r * 129;
      int o = ob + r, k = q * 2;
      float2 w2 = *(const float2*)(w + o * 258 + k);
      int g = o >> 5, col = o & 31;
      int ks = k >> 4, hi = (k >> 3) & 1, j = k & 7;
      uint32_t pk = (uint32_t)f2bf(w2.x) | ((uint32_t)f2bf(w2.y) << 16);
      *(uint32_t*)(dst + (((g * NKS + ks) * 64 + hi * 32 + col) << 3) + j) = pk;
    }
    // k 258 (bias) and 259..271 (zero)
    for (int i = threadIdx.x; i < 4 * 14; i += 256) {
      int r = i / 14, kk = 258 + (i - r * 14);
      int o = ob + r;
      int g = o >> 5, col = o & 31;
      int ks = kk >> 4, hi = (kk >> 3) & 1, j = kk & 7;
      dst[(((g * NKS + ks) * 64 + hi * 32 + col) << 3) + j] =
          (kk == 258) ? f2bf(bb[o]) : (unsigned short)0;
    }
  } else {
    int idx = (bid - 512) * 256 + threadIdx.x;  // [0, 262144)
    int fc = idx & 15, m = (idx >> 4) & 63, o = idx >> 10;
    const f32x4* wo = (const f32x4*)(wout + o * 256 + fc * 16);
    const f32x4* vm = (const f32x4*)(v + m * 256 + fc * 16);
    float s = 0.f;
#pragma unroll
    for (int f = 0; f < 4; ++f) {
      f32x4 a = wo[f], bvv = vm[f];
      s += a[0]*bvv[0] + a[1]*bvv[1] + a[2]*bvv[2] + a[3]*bvv[3];
    }
    s += __shfl_xor(s, 1, 64);
    s += __shfl_xor(s, 2, 64);
    s += __shfl_xor(s, 4, 64);
    s += __shfl_xor(s, 8, 64);
    if (fc == 0) wsp[WVP_OFF + o * 64 + m] = f2bf(s);
  }
}

// =====================================================================
// fused v5: 64 px/block, 256 blocks, 16 waves, 1 block/CU (52 KB LDS).
// Per wave: 2 o-tiles x 2 px-tiles = 4 acc (64 AGPR) + depth-2 A-ring.
// Per-block TILE ROTATION (ti0 = (2*wid + 2*(bid&15)) & 31) de-phases
// which weight lines concurrent blocks hit in L2 (anti-same-line-
// contention). attnM write uses m0 = 2*ti, everything else m-agnostic.
// Barrier trick: no sync between qbar atomics and k K-loop.
// =====================================================================
#define PXB 64   // pixels per block
#define KP 296   // xp row stride in shorts
#define QS 66    // qbar row stride (floats)
#define AT 72    // attnM row stride (shorts)

__global__ __launch_bounds__(1024, 4) void fused_kernel(
    const float* __restrict__ x, const float* __restrict__ pos,
    const unsigned short* __restrict__ wsp, const float* __restrict__ bout,
    float* __restrict__ out) {
  __shared__ __align__(16) unsigned short xp[PXB * KP];        // 37888 B
  __shared__ __align__(16) float qbarL[16 * QS];               // 4224 B
  __shared__ __align__(16) unsigned short attnM[PXB * AT];     // 9216 B
  __shared__ float boutL[256];                                 // 1024 B

  const int tid = threadIdx.x;
  const int lane = tid & 63;
  const int wid = __builtin_amdgcn_readfirstlane(tid >> 6);
  const int px = lane & 31, q2 = lane >> 5;
  const int bid = blockIdx.x;
  const int P0 = bid * PXB;
  const int b = P0 >> 12, s0 = P0 & 4095;

  // Rotated per-wave tile assignment (ti0 even, ti1 = ti0+1)
  const int rot2 = (bid & 15) << 1;
  const int ti0 = (2 * wid + rot2) & 31;
  const int ti1 = ti0 + 1;
  const unsigned short* wq0 = wsp + WQF_OFF + ti0 * (NKS * 512) + lane * 8;
  const unsigned short* wq1 = wsp + WQF_OFF + ti1 * (NKS * 512) + lane * 8;
  const unsigned short* wk0 = wsp + WKF_OFF + ti0 * (NKS * 512) + lane * 8;
  const unsigned short* wk1 = wsp + WKF_OFF + ti1 * (NKS * 512) + lane * 8;

  // ---- stage xp[p][c]: lanes along pixels => coalesced segments ----
  uint32_t* xp32 = (uint32_t*)xp;
  {
    const float* xrow = x + b * 256 * 4096 + s0;
    float v0[8], v1[8];
#pragma unroll
    for (int it = 0; it < 8; ++it) {
      int item = tid + it * 1024;                 // 0..8191
      int pp = item & 63, dcol = item >> 6;       // dcol 0..127
      v0[it] = xrow[(2 * dcol) * 4096 + pp];
      v1[it] = xrow[(2 * dcol + 1) * 4096 + pp];
    }
#pragma unroll
    for (int it = 0; it < 8; ++it) {
      int item = tid + it * 1024;
      int pp = item & 63, dcol = item >> 6;
      xp32[pp * 148 + dcol] =
          (uint32_t)f2bf(v0[it]) | ((uint32_t)f2bf(v1[it]) << 16);
    }
    // tail cols: dcol 128 = (pos_y,pos_x), 129 = (1,0) bias, 130..135 = 0
    if (tid < 512) {
      int pp = tid & 63, dcol = 128 + (tid >> 6);
      float t0 = 0.f, t1 = 0.f;
      if (dcol == 128) { t0 = pos[s0 + pp]; t1 = pos[4096 + s0 + pp]; }
      else if (dcol == 129) { t0 = 1.0f; }
      xp32[pp * 148 + dcol] = (uint32_t)f2bf(t0) | ((uint32_t)f2bf(t1) << 16);
    }
  }
  if (tid < 256) boutL[tid] = bout[tid];
  for (int i = tid; i < 16 * QS; i += 1024) qbarL[i] = 0.f;
  __syncthreads();

// K-loop: depth-2 register prefetch ring (4 A-loads in flight), fully
// unrolled => ring indices (ks&1) are compile-time constants (no scratch).
#define PHASE(W0, W1) do {                                                \
    bf16x8 ra0[2], ra1[2];                                                \
    ra0[0] = *(const bf16x8*)((W0));                                      \
    ra1[0] = *(const bf16x8*)((W1));                                      \
    ra0[1] = *(const bf16x8*)((W0) + 512);                                \
    ra1[1] = *(const bf16x8*)((W1) + 512);                                \
    _Pragma("unroll")                                                     \
    for (int ks = 0; ks < NKS; ++ks) {                                    \
      bf16x8 _A0 = ra0[ks & 1], _A1 = ra1[ks & 1];                        \
      if (ks + 2 < NKS) {                                                 \
        ra0[ks & 1] = *(const bf16x8*)((W0) + (ks + 2) * 512);            \
        ra1[ks & 1] = *(const bf16x8*)((W1) + (ks + 2) * 512);            \
      }                                                                   \
      bf16x8 _b0 = *(const bf16x8*)&xp[px * KP + ks * 16 + q2 * 8];       \
      bf16x8 _b1 = *(const bf16x8*)&xp[(32 + px) * KP + ks * 16 + q2 * 8];\
      acc00 = __builtin_amdgcn_mfma_f32_32x32x16_bf16(_A0, _b0, acc00, 0, 0, 0); \
      acc01 = __builtin_amdgcn_mfma_f32_32x32x16_bf16(_A0, _b1, acc01, 0, 0, 0); \
      acc10 = __builtin_amdgcn_mfma_f32_32x32x16_bf16(_A1, _b0, acc10, 0, 0, 0); \
      acc11 = __builtin_amdgcn_mfma_f32_32x32x16_bf16(_A1, _b1, acc11, 0, 0, 0); \
    }                                                                     \
  } while (0)

  // ================= q phase =================
  f32x16 acc00 = (f32x16)0.f, acc01 = (f32x16)0.f,
         acc10 = (f32x16)0.f, acc11 = (f32x16)0.f;
  PHASE(wq0, wq1);

  // normalize per m; accumulate qbar partials
  {
    float qsum[2][8];
#pragma unroll
    for (int nt = 0; nt < 2; ++nt)
#pragma unroll
      for (int r = 0; r < 8; ++r) qsum[nt][r] = 0.f;
#pragma unroll
    for (int ot = 0; ot < 2; ++ot) {
#pragma unroll
      for (int nt = 0; nt < 2; ++nt) {
        const f32x16 a = ot ? (nt ? acc11 : acc10) : (nt ? acc01 : acc00);
        float s20 = 0.f, s21 = 0.f;
#pragma unroll
        for (int r = 0; r < 8; ++r) {
          s20 = fmaf(a[r], a[r], s20);
          s21 = fmaf(a[r + 8], a[r + 8], s21);
        }
        s20 += __shfl_xor(s20, 32, 64);
        s21 += __shfl_xor(s21, 32, 64);
        float i0 = 1.0f / fmaxf(sqrtf(s20), EPSN);
        float i1 = 1.0f / fmaxf(sqrtf(s21), EPSN);
#pragma unroll
        for (int r = 0; r < 8; ++r) qsum[nt][r] += a[r] * i0 + a[r + 8] * i1;
      }
    }
#pragma unroll
    for (int nt = 0; nt < 2; ++nt)
#pragma unroll
      for (int r = 0; r < 8; ++r) {
        int j = (r & 3) + ((r >> 2) << 3) + (q2 << 2);
        atomicAdd(&qbarL[j * QS + nt * 32 + px], qsum[nt][r] * (1.0f / 64.0f));
      }
  }
  // NO barrier here: k-phase MFMAs don't read qbarL; the barrier below
  // (after the k K-loop) orders the qbar atomics vs the qb reads.

  // ================= k phase =================
  acc00 = (f32x16)0.f; acc01 = (f32x16)0.f;
  acc10 = (f32x16)0.f; acc11 = (f32x16)0.f;
  PHASE(wk0, wk1);
  __syncthreads();

  {
    float qb[2][8];
#pragma unroll
    for (int nt = 0; nt < 2; ++nt)
#pragma unroll
      for (int r = 0; r < 8; ++r) {
        int j = (r & 3) + ((r >> 2) << 3) + (q2 << 2);
        qb[nt][r] = qbarL[j * QS + nt * 32 + px];
      }
#pragma unroll
    for (int ot = 0; ot < 2; ++ot) {
      const int m0 = (ot ? ti1 : ti0) * 2;
#pragma unroll
      for (int nt = 0; nt < 2; ++nt) {
        const f32x16 a = ot ? (nt ? acc11 : acc10) : (nt ? acc01 : acc00);
        float s20 = 0.f, s21 = 0.f, sp0 = 0.f, sp1 = 0.f;
#pragma unroll
        for (int r = 0; r < 8; ++r) {
          s20 = fmaf(a[r], a[r], s20);         sp0 = fmaf(qb[nt][r], a[r], sp0);
          s21 = fmaf(a[r + 8], a[r + 8], s21); sp1 = fmaf(qb[nt][r], a[r + 8], sp1);
        }
        s20 += __shfl_xor(s20, 32, 64);
        s21 += __shfl_xor(s21, 32, 64);
        sp0 += __shfl_xor(sp0, 32, 64);
        sp1 += __shfl_xor(sp1, 32, 64);
        if (q2 == 0) {
          attnM[(nt * 32 + px) * AT + m0]     = f2bf(sp0 / fmaxf(sqrtf(s20), EPSN));
          attnM[(nt * 32 + px) * AT + m0 + 1] = f2bf(sp1 / fmaxf(sqrtf(s21), EPSN));
        }
      }
    }
  }
  __syncthreads();

  // ================= epilogue: out = x + bout + WVt @ attn =================
  {
    const int otile = wid >> 1, pxt = wid & 1;
    f32x16 e = (f32x16)0.f;
    const unsigned short* wv = wsp + WVP_OFF + (otile * 32 + px) * 64 + q2 * 8;
    const unsigned short* ab = &attnM[(pxt * 32 + px) * AT + q2 * 8];
#pragma unroll
    for (int ks = 0; ks < 4; ++ks) {
      bf16x8 av = *(const bf16x8*)(wv + ks * 16);
      bf16x8 bv = *(const bf16x8*)(ab + ks * 16);
      e = __builtin_amdgcn_mfma_f32_32x32x16_bf16(av, bv, e, 0, 0, 0);
    }
#pragma unroll
    for (int r = 0; r < 16; ++r) {
      const int o = otile * 32 + (r & 3) + ((r >> 2) << 3) + (q2 << 2);
      const int p = pxt * 32 + px;
      const int gi = (b * 256 + o) * 4096 + s0 + p;
      out[gi] = x[gi] + boutL[o] + e[r];
    }
  }
#undef PHASE
}

// =====================================================================
extern "C" void kernel_launch(void* const* d_in, const int* in_sizes, int n_in,
                              void* d_out, int out_size, void* d_ws, size_t ws_size,
                              hipStream_t stream) {
  const float* x    = (const float*)d_in[0];
  const float* pos  = (const float*)d_in[1];
  const float* wq   = (const float*)d_in[2];
  const float* bq   = (const float*)d_in[3];
  const float* wk   = (const float*)d_in[4];
  const float* bk   = (const float*)d_in[5];
  const float* v    = (const float*)d_in[6];
  const float* wout = (const float*)d_in[7];
  const float* bout = (const float*)d_in[8];
  float* out = (float*)d_out;
  unsigned short* wsp = (unsigned short*)d_ws;

  hipLaunchKernelGGL(prep_kernel, dim3(1536), dim3(256), 0, stream,
                     wq, bq, wk, bk, v, wout, wsp);
  hipLaunchKernelGGL(fused_kernel, dim3(256), dim3(1024), 0, stream,
                     x, pos, wsp, bout, out);
}

// Round 6
// 126.655 us; speedup vs baseline: 1.3781x; 1.0185x over previous
//
#include <hip/hip_runtime.h>
#include <stdint.h>

#define EPSN 1e-12f

typedef float f32x16 __attribute__((ext_vector_type(16)));
typedef float f32x4 __attribute__((ext_vector_type(4)));
typedef __bf16 bf16x8 __attribute__((ext_vector_type(8)));
typedef unsigned short u16x4 __attribute__((ext_vector_type(4)));

// ---- bf16 helpers ----
__device__ __forceinline__ unsigned short f2bf(float f) {
  union { float f; unsigned int u; } v; v.f = f;
  unsigned int u = v.u + 0x7FFFu + ((v.u >> 16) & 1u);
  return (unsigned short)(u >> 16);
}
__device__ __forceinline__ float bf2f(unsigned short h) {
  union { float f; unsigned int u; } v; v.u = ((unsigned int)h) << 16;
  return v.f;
}

// ---- workspace layout (ushort offsets) ----
// Fragment-major packed weights for 32x32x16 MFMA, K padded 258(+bias)->272:
//   addr = ((tile*NKS + ks)*64 + hi*32 + col)*8 + j
//   value = W[o = tile*32 + col][k = ks*16 + hi*8 + j]  (k=258 bias, >258 zero)
#define NKS 17
#define WQF_OFF 0
#define WKF_OFF (32 * NKS * 64 * 8)
#define WVP_OFF (2 * 32 * NKS * 64 * 8)

// =====================================================================
// prep: blocks [0,512) pack wq/wk (4 o-rows each); [512,1536) WVt.
// =====================================================================
__global__ __launch_bounds__(256) void prep_kernel(
    const float* __restrict__ wq, const float* __restrict__ bq,
    const float* __restrict__ wk, const float* __restrict__ bk,
    const float* __restrict__ v, const float* __restrict__ wout,
    unsigned short* __restrict__ wsp) {
  int bid = blockIdx.x;
  if (bid < 512) {
    int isK = bid >= 256;
    int ob = (bid & 255) * 4;
    const float* w = isK ? wk : wq;
    const float* bb = isK ? bk : bq;
    unsigned short* dst = wsp + (isK ? WKF_OFF : WQF_OFF);
    for (int i = threadIdx.x; i < 4 * 129; i += 256) {
      int r = i / 129, q = i - r * 129;
      int o = ob + r, k = q * 2;
      float2 w2 = *(const float2*)(w + o * 258 + k);
      int g = o >> 5, col = o & 31;
      int ks = k >> 4, hi = (k >> 3) & 1, j = k & 7;
      uint32_t pk = (uint32_t)f2bf(w2.x) | ((uint32_t)f2bf(w2.y) << 16);
      *(uint32_t*)(dst + (((g * NKS + ks) * 64 + hi * 32 + col) << 3) + j) = pk;
    }
    for (int i = threadIdx.x; i < 4 * 14; i += 256) {
      int r = i / 14, kk = 258 + (i - r * 14);
      int o = ob + r;
      int g = o >> 5, col = o & 31;
      int ks = kk >> 4, hi = (kk >> 3) & 1, j = kk & 7;
      dst[(((g * NKS + ks) * 64 + hi * 32 + col) << 3) + j] =
          (kk == 258) ? f2bf(bb[o]) : (unsigned short)0;
    }
  } else {
    int idx = (bid - 512) * 256 + threadIdx.x;
    int fc = idx & 15, m = (idx >> 4) & 63, o = idx >> 10;
    const f32x4* wo = (const f32x4*)(wout + o * 256 + fc * 16);
    const f32x4* vm = (const f32x4*)(v + m * 256 + fc * 16);
    float s = 0.f;
#pragma unroll
    for (int f = 0; f < 4; ++f) {
      f32x4 a = wo[f], bvv = vm[f];
      s += a[0]*bvv[0] + a[1]*bvv[1] + a[2]*bvv[2] + a[3]*bvv[3];
    }
    s += __shfl_xor(s, 1, 64);
    s += __shfl_xor(s, 2, 64);
    s += __shfl_xor(s, 4, 64);
    s += __shfl_xor(s, 8, 64);
    if (fc == 0) wsp[WVP_OFF + o * 64 + m] = f2bf(s);
  }
}

// =====================================================================
// fused v6: 64 px/block, 256 blocks, 16 waves, 1 block/CU.
// Depth-3 A-ring (6 loads in flight) + per-wave ks-rotation (waves walk
// the 17 K-slices starting at slice wid -> de-phased loads/stalls).
// q-ring fill hides under staging; k-ring fill hides under q-norm.
// float4 staging; epilogue residual read from xp (LDS, bf16).
// =====================================================================
#define PXB 64   // pixels per block
#define KP 296   // xp row stride in shorts
#define QS 66    // qbar row stride (floats)
#define AT 72    // attnM row stride (shorts)

__global__ __launch_bounds__(1024, 4) void fused_kernel(
    const float* __restrict__ x, const float* __restrict__ pos,
    const unsigned short* __restrict__ wsp, const float* __restrict__ bout,
    float* __restrict__ out) {
  __shared__ __align__(16) unsigned short xp[PXB * KP];        // 37888 B
  __shared__ __align__(16) float qbarL[16 * QS];               // 4224 B
  __shared__ __align__(16) unsigned short attnM[PXB * AT];     // 9216 B
  __shared__ float boutL[256];                                 // 1024 B

  const int tid = threadIdx.x;
  const int lane = tid & 63;
  const int wid = __builtin_amdgcn_readfirstlane(tid >> 6);
  const int px = lane & 31, q2 = lane >> 5;
  const int P0 = blockIdx.x * PXB;
  const int b = P0 >> 12, s0 = P0 & 4095;

  // Per-wave A-stream bases (tile0 = 2*wid, tile1 = 2*wid+1; +lane frag)
  const int wtoff = (2 * wid) * NKS * 512 + lane * 8;
  const unsigned short* wqf = wsp + WQF_OFF + wtoff;
  const unsigned short* wkf = wsp + WKF_OFF + wtoff;

  const int kbase = wid;  // 0..15 < NKS: per-wave K-slice rotation

  bf16x8 ring0[3], ring1[3];
#define RING_FILL(WB) do {                                                \
    _Pragma("unroll")                                                     \
    for (int s = 0; s < 3; ++s) {                                         \
      int kp = kbase + s; if (kp >= NKS) kp -= NKS;                       \
      ring0[s] = *(const bf16x8*)((WB) + kp * 512);                       \
      ring1[s] = *(const bf16x8*)((WB) + NKS * 512 + kp * 512);           \
    }                                                                     \
  } while (0)

  // q-ring fill issued first: L2 latency hides under the staging phase.
  RING_FILL(wqf);

  // ---- stage xp[p][c] via float4 (16B/lane, coalesced 256B rows) ----
  uint32_t* xp32 = (uint32_t*)xp;
  {
    const float* xrow = x + b * 256 * 4096 + s0;
    f32x4 lo[2], hi[2];
#pragma unroll
    for (int it = 0; it < 2; ++it) {
      int idx = tid + it * 1024;                  // 0..2047
      int g = idx & 15, dcol = idx >> 4;          // dcol 0..127
      lo[it] = *(const f32x4*)(xrow + (2 * dcol) * 4096 + 4 * g);
      hi[it] = *(const f32x4*)(xrow + (2 * dcol + 1) * 4096 + 4 * g);
    }
#pragma unroll
    for (int it = 0; it < 2; ++it) {
      int idx = tid + it * 1024;
      int g = idx & 15, dcol = idx >> 4;
#pragma unroll
      for (int j = 0; j < 4; ++j) {
        int pp = 4 * g + j;
        xp32[pp * 148 + dcol] =
            (uint32_t)f2bf(lo[it][j]) | ((uint32_t)f2bf(hi[it][j]) << 16);
      }
    }
    // tail cols: dcol 128 = (pos_y,pos_x), 129 = (1,0) bias, 130..135 = 0
    if (tid < 512) {
      int pp = tid & 63, dcol = 128 + (tid >> 6);
      float t0 = 0.f, t1 = 0.f;
      if (dcol == 128) { t0 = pos[s0 + pp]; t1 = pos[4096 + s0 + pp]; }
      else if (dcol == 129) { t0 = 1.0f; }
      xp32[pp * 148 + dcol] = (uint32_t)f2bf(t0) | ((uint32_t)f2bf(t1) << 16);
    }
  }
  if (tid < 256) boutL[tid] = bout[tid];
  for (int i = tid; i < 16 * QS; i += 1024) qbarL[i] = 0.f;
  __syncthreads();

// K-loop: rotated slice order (kbase+i mod 17), depth-3 register ring,
// fully unrolled => ring index i%3 static (no scratch).
#define PHASE(WB) do {                                                    \
    _Pragma("unroll")                                                     \
    for (int i = 0; i < NKS; ++i) {                                       \
      int ks = kbase + i; if (ks >= NKS) ks -= NKS;                       \
      bf16x8 _A0 = ring0[i % 3], _A1 = ring1[i % 3];                      \
      if (i + 3 < NKS) {                                                  \
        int kp = ks + 3; if (kp >= NKS) kp -= NKS;                        \
        ring0[i % 3] = *(const bf16x8*)((WB) + kp * 512);                 \
        ring1[i % 3] = *(const bf16x8*)((WB) + NKS * 512 + kp * 512);     \
      }                                                                   \
      const int boff = ks * 16 + q2 * 8;                                  \
      bf16x8 _b0 = *(const bf16x8*)&xp[px * KP + boff];                   \
      bf16x8 _b1 = *(const bf16x8*)&xp[(32 + px) * KP + boff];            \
      acc00 = __builtin_amdgcn_mfma_f32_32x32x16_bf16(_A0, _b0, acc00, 0, 0, 0); \
      acc01 = __builtin_amdgcn_mfma_f32_32x32x16_bf16(_A0, _b1, acc01, 0, 0, 0); \
      acc10 = __builtin_amdgcn_mfma_f32_32x32x16_bf16(_A1, _b0, acc10, 0, 0, 0); \
      acc11 = __builtin_amdgcn_mfma_f32_32x32x16_bf16(_A1, _b1, acc11, 0, 0, 0); \
    }                                                                     \
  } while (0)

  // ================= q phase =================
  f32x16 acc00 = (f32x16)0.f, acc01 = (f32x16)0.f,
         acc10 = (f32x16)0.f, acc11 = (f32x16)0.f;
  PHASE(wqf);

  // k-ring fill: latency hides under the norm section below.
  RING_FILL(wkf);

  // normalize per m; accumulate qbar partials
  {
    float qsum[2][8];
#pragma unroll
    for (int nt = 0; nt < 2; ++nt)
#pragma unroll
      for (int r = 0; r < 8; ++r) qsum[nt][r] = 0.f;
#pragma unroll
    for (int ot = 0; ot < 2; ++ot) {
#pragma unroll
      for (int nt = 0; nt < 2; ++nt) {
        const f32x16 a = ot ? (nt ? acc11 : acc10) : (nt ? acc01 : acc00);
        float s20 = 0.f, s21 = 0.f;
#pragma unroll
        for (int r = 0; r < 8; ++r) {
          s20 = fmaf(a[r], a[r], s20);
          s21 = fmaf(a[r + 8], a[r + 8], s21);
        }
        s20 += __shfl_xor(s20, 32, 64);
        s21 += __shfl_xor(s21, 32, 64);
        float i0 = 1.0f / fmaxf(sqrtf(s20), EPSN);
        float i1 = 1.0f / fmaxf(sqrtf(s21), EPSN);
#pragma unroll
        for (int r = 0; r < 8; ++r) qsum[nt][r] += a[r] * i0 + a[r + 8] * i1;
      }
    }
#pragma unroll
    for (int nt = 0; nt < 2; ++nt)
#pragma unroll
      for (int r = 0; r < 8; ++r) {
        int j = (r & 3) + ((r >> 2) << 3) + (q2 << 2);
        atomicAdd(&qbarL[j * QS + nt * 32 + px], qsum[nt][r] * (1.0f / 64.0f));
      }
  }
  // NO barrier here: k-phase MFMAs don't read qbarL; the barrier below
  // (after the k K-loop) orders the qbar atomics vs the qb reads.

  // ================= k phase =================
  acc00 = (f32x16)0.f; acc01 = (f32x16)0.f;
  acc10 = (f32x16)0.f; acc11 = (f32x16)0.f;
  PHASE(wkf);
  __syncthreads();

  {
    float qb[2][8];
#pragma unroll
    for (int nt = 0; nt < 2; ++nt)
#pragma unroll
      for (int r = 0; r < 8; ++r) {
        int j = (r & 3) + ((r >> 2) << 3) + (q2 << 2);
        qb[nt][r] = qbarL[j * QS + nt * 32 + px];
      }
#pragma unroll
    for (int ot = 0; ot < 2; ++ot) {
#pragma unroll
      for (int nt = 0; nt < 2; ++nt) {
        const f32x16 a = ot ? (nt ? acc11 : acc10) : (nt ? acc01 : acc00);
        float s20 = 0.f, s21 = 0.f, sp0 = 0.f, sp1 = 0.f;
#pragma unroll
        for (int r = 0; r < 8; ++r) {
          s20 = fmaf(a[r], a[r], s20);         sp0 = fmaf(qb[nt][r], a[r], sp0);
          s21 = fmaf(a[r + 8], a[r + 8], s21); sp1 = fmaf(qb[nt][r], a[r + 8], sp1);
        }
        s20 += __shfl_xor(s20, 32, 64);
        s21 += __shfl_xor(s21, 32, 64);
        sp0 += __shfl_xor(sp0, 32, 64);
        sp1 += __shfl_xor(sp1, 32, 64);
        if (q2 == 0) {
          int m0 = wid * 4 + ot * 2;
          attnM[(nt * 32 + px) * AT + m0]     = f2bf(sp0 / fmaxf(sqrtf(s20), EPSN));
          attnM[(nt * 32 + px) * AT + m0 + 1] = f2bf(sp1 / fmaxf(sqrtf(s21), EPSN));
        }
      }
    }
  }
  __syncthreads();

  // ======= epilogue: out = x + bout + WVt @ attn (x from xp, bf16) =======
  {
    const int otile = wid >> 1, pxt = wid & 1;
    f32x16 e = (f32x16)0.f;
    const unsigned short* wv = wsp + WVP_OFF + (otile * 32 + px) * 64 + q2 * 8;
    const unsigned short* ab = &attnM[(pxt * 32 + px) * AT + q2 * 8];
#pragma unroll
    for (int ks = 0; ks < 4; ++ks) {
      bf16x8 av = *(const bf16x8*)(wv + ks * 16);
      bf16x8 bv = *(const bf16x8*)(ab + ks * 16);
      e = __builtin_amdgcn_mfma_f32_32x32x16_bf16(av, bv, e, 0, 0, 0);
    }
    const int p = pxt * 32 + px;
    const unsigned short* xl = &xp[p * KP + otile * 32 + (q2 << 2)];
#pragma unroll
    for (int rq = 0; rq < 4; ++rq) {
      u16x4 xq = *(const u16x4*)(xl + 8 * rq);
#pragma unroll
      for (int j = 0; j < 4; ++j) {
        const int r = rq * 4 + j;
        const int o = otile * 32 + j + (rq << 3) + (q2 << 2);
        const int gi = (b * 256 + o) * 4096 + s0 + p;
        out[gi] = bf2f(xq[j]) + boutL[o] + e[r];
      }
    }
  }
#undef PHASE
#undef RING_FILL
}

// =====================================================================
extern "C" void kernel_launch(void* const* d_in, const int* in_sizes, int n_in,
                              void* d_out, int out_size, void* d_ws, size_t ws_size,
                              hipStream_t stream) {
  const float* x    = (const float*)d_in[0];
  const float* pos  = (const float*)d_in[1];
  const float* wq   = (const float*)d_in[2];
  const float* bq   = (const float*)d_in[3];
  const float* wk   = (const float*)d_in[4];
  const float* bk   = (const float*)d_in[5];
  const float* v    = (const float*)d_in[6];
  const float* wout = (const float*)d_in[7];
  const float* bout = (const float*)d_in[8];
  float* out = (float*)d_out;
  unsigned short* wsp = (unsigned short*)d_ws;

  hipLaunchKernelGGL(prep_kernel, dim3(1536), dim3(256), 0, stream,
                     wq, bq, wk, bk, v, wout, wsp);
  hipLaunchKernelGGL(fused_kernel, dim3(256), dim3(1024), 0, stream,
                     x, pos, wsp, bout, out);
}